// Round 1
// 433.783 us; speedup vs baseline: 1.0531x; 1.0531x over previous
//
#include <hip/hip_runtime.h>
#include <stdint.h>

#define FH 64
#define FW 64
#define CIN 1536
#define C3C 512
#define C4C 1024
#define COUT 512
#define BATCH 16
#define NPIX 4096
#define NBOX 10
#define MPAD 256   // 10 boxes * 25 bins = 250, padded

typedef float v4f __attribute__((ext_vector_type(4)));

#define GLOAD_LDS16(g, l) __builtin_amdgcn_global_load_lds( \
    (const __attribute__((address_space(1))) void*)(g),     \
    (__attribute__((address_space(3))) void*)(l), 16, 0, 0)

// pack 4 floats -> 4 fp8 e4m3 bytes in one u32 (byte k = f[k])
__device__ __forceinline__ uint32_t pack4_fp8(float a, float b, float c, float d) {
    int lo = __builtin_amdgcn_cvt_pk_fp8_f32(a, b, 0, false);
    int v  = __builtin_amdgcn_cvt_pk_fp8_f32(c, d, lo, true);
    return (uint32_t)v;
}
__device__ __forceinline__ unsigned char f32_to_fp8(float a) {
    return (unsigned char)(__builtin_amdgcn_cvt_pk_fp8_f32(a, a, 0, false) & 0xff);
}

// ---------------- BN constant folding (W was scaled x16 -> scale/16) -------
__global__ void prep_bn(const float* __restrict__ bng, const float* __restrict__ bnb,
                        const float* __restrict__ bnm, const float* __restrict__ bnv,
                        const float* __restrict__ bconv,
                        float* __restrict__ scale, float* __restrict__ shift) {
    int o = threadIdx.x;
    if (o < COUT) {
        float inv = bng[o] / sqrtf(bnv[o] + 1e-5f);
        scale[o] = inv * 0.0625f;             // /16: W quantized as W*16
        shift[o] = bnb[o] + inv * (bconv[o] - bnm[o]);
    }
}

// ---------------- W f32 -> fp8 (x16) ---------------------------------------
__global__ void conv_w(const float* __restrict__ w, uint32_t* __restrict__ w8, int n4) {
    int i = blockIdx.x * 256 + threadIdx.x;
    if (i < n4) {
        float4 f = *(const float4*)(w + i * 4);
        w8[i] = pack4_fp8(f.x * 16.0f, f.y * 16.0f, f.z * 16.0f, f.w * 16.0f);
    }
}

// ---------------- build fusedT[b][pix][c] fp8 (K-major) --------------------
// tile: 128 channels x 64 px (one y row). LDS u32 = 4 packed channels.
__global__ __launch_bounds__(256) void build_fusedT(const float* __restrict__ c3,
                                                    const float* __restrict__ c4,
                                                    unsigned char* __restrict__ fusedT) {
    __shared__ uint32_t lds[64 * 36];
    int ct = blockIdx.x;          // 0..11; <4 -> c3, else c4
    int y  = blockIdx.y;
    int b  = blockIdx.z;
    int t  = threadIdx.x;
    int pg = t & 15;              // pixel quad: px 4pg..4pg+3
    int cq = t >> 4;              // 0..15; cquad = cq + 16r

    #pragma unroll
    for (int r = 0; r < 2; ++r) {
        int cquad = cq + 16 * r;
        float vv[4][4];           // [channel][pixel]
        if (ct < 4) {
            int ch = ct * 128 + 4 * cquad;
            const float* src = c3 + (((size_t)(b * C3C + ch) * FH + y) * FW) + 4 * pg;
            #pragma unroll
            for (int k = 0; k < 4; ++k) {
                float4 f = *(const float4*)(src + (size_t)k * (FH * FW));
                vv[k][0] = f.x; vv[k][1] = f.y; vv[k][2] = f.z; vv[k][3] = f.w;
            }
        } else {
            int ch = ct * 128 - 512 + 4 * cquad;
            int jy = y >> 1;
            int jyB = min(max(jy + ((y & 1) ? 1 : -1), 0), 31);
            int k0 = 2 * pg;
            int km = max(k0 - 1, 0), kp = min(k0 + 2, 31);
            const float* base = c4 + (size_t)(b * C4C + ch) * 1024;
            #pragma unroll
            for (int k = 0; k < 4; ++k) {
                const float* pc = base + (size_t)k * 1024;
                const float* r0 = pc + jy * 32;
                const float* r1 = pc + jyB * 32;
                float rbm = 0.75f * r0[km]     + 0.25f * r1[km];
                float rb0 = 0.75f * r0[k0]     + 0.25f * r1[k0];
                float rb1 = 0.75f * r0[k0 + 1] + 0.25f * r1[k0 + 1];
                float rbp = 0.75f * r0[kp]     + 0.25f * r1[kp];
                vv[k][0] = 0.75f * rb0 + 0.25f * rbm;
                vv[k][1] = 0.75f * rb0 + 0.25f * rb1;
                vv[k][2] = 0.75f * rb1 + 0.25f * rb0;
                vv[k][3] = 0.75f * rb1 + 0.25f * rbp;
            }
        }
        #pragma unroll
        for (int i = 0; i < 4; ++i)
            lds[(4 * pg + i) * 36 + cquad] = pack4_fp8(vv[0][i], vv[1][i], vv[2][i], vv[3][i]);
    }
    __syncthreads();
    // write: 64 px x 128 B; thread covers 2 x 16 B
    int g = t & 7;                 // 16-channel group
    #pragma unroll
    for (int rr = 0; rr < 2; ++rr) {
        int px = (t >> 3) + 32 * rr;
        uint4 w = *(const uint4*)(&lds[px * 36 + 4 * g]);
        *(uint4*)(fusedT + ((size_t)b * NPIX + y * FW + px) * CIN + ct * 128 + g * 16) = w;
    }
}

// ---------------- fp8 GEMM + BN + ReLU, BK=64, channel-major fp8 out -------
// LDS swizzle key: (row>>1)&3, NOT row&3.  bank = (row&1)*16 + chunk'*4 + i8*2;
// row&3 as key makes bank a function of row&3 only -> 4-way conflict on every
// ds_read_b64 (measured 3.775e7 = 12 extra cyc x 384 reads/wave x 8192 waves).
// (row>>1)&3 makes bank depend on row&7 -> 8 bank-pairs x 2 lanes = free.
__global__ __launch_bounds__(256) void gemm_bn_relu(
        const unsigned char* __restrict__ w8,
        const unsigned char* __restrict__ fusedT,
        const float* __restrict__ scale, const float* __restrict__ shift,
        unsigned char* __restrict__ attr) {
    __shared__ __align__(16) unsigned char lds_a[128 * 64];
    __shared__ __align__(16) unsigned char lds_b[128 * 64];
    int t  = threadIdx.x;
    int n0 = blockIdx.x * 128;   // pixel tile
    int o0 = blockIdx.y * 128;   // out-channel tile
    int b  = blockIdx.z;
    int wave = t >> 6, lane = t & 63;
    int wm = wave & 1, wn = wave >> 1;
    int quad = lane >> 4, l16 = lane & 15;
    const unsigned char* fb = fusedT + (size_t)b * NPIX * CIN;

    v4f acc[4][4];
    #pragma unroll
    for (int i = 0; i < 4; ++i)
        #pragma unroll
        for (int j = 0; j < 4; ++j) acc[i][j] = (v4f)0.0f;

    // staging: row = t>>2 (and +64), 16-B chunk (t&3) XOR-swizzled by (row>>1)&3
    int row = t >> 2;
    int cg  = (t & 3) ^ ((row >> 1) & 3);
    const unsigned char* ga0 = w8 + (size_t)(o0 + row) * CIN + cg * 16;
    const unsigned char* ga1 = w8 + (size_t)(o0 + row + 64) * CIN + cg * 16;
    const unsigned char* gb0 = fb + (size_t)(n0 + row) * CIN + cg * 16;
    const unsigned char* gb1 = fb + (size_t)(n0 + row + 64) * CIN + cg * 16;
    unsigned char* la0 = lds_a + t * 16;
    unsigned char* la1 = lds_a + 4096 + t * 16;
    unsigned char* lb0 = lds_b + t * 16;
    unsigned char* lb1 = lds_b + 4096 + t * 16;

    int ra[4], rb[4];
    #pragma unroll
    for (int i = 0; i < 4; ++i) { ra[i] = wm * 64 + i * 16 + l16; rb[i] = wn * 64 + i * 16 + l16; }
    int q2 = quad >> 1, q1 = (quad & 1) * 8;

    for (int kt = 0; kt < CIN / 64; ++kt) {
        __syncthreads();
        GLOAD_LDS16(ga0, la0);
        GLOAD_LDS16(ga1, la1);
        GLOAD_LDS16(gb0, lb0);
        GLOAD_LDS16(gb1, lb1);
        ga0 += 64; ga1 += 64; gb0 += 64; gb1 += 64;
        __syncthreads();

        #pragma unroll
        for (int s = 0; s < 2; ++s) {
            long af[4], bf[4];
            #pragma unroll
            for (int i = 0; i < 4; ++i) {
                int pa = (2 * s + q2) ^ ((ra[i] >> 1) & 3);
                af[i] = *(const long*)(lds_a + ra[i] * 64 + pa * 16 + q1);
                int pb = (2 * s + q2) ^ ((rb[i] >> 1) & 3);
                bf[i] = *(const long*)(lds_b + rb[i] * 64 + pb * 16 + q1);
            }
            #pragma unroll
            for (int i = 0; i < 4; ++i)
                #pragma unroll
                for (int j = 0; j < 4; ++j)
                    acc[i][j] = __builtin_amdgcn_mfma_f32_16x16x32_fp8_fp8(af[i], bf[j], acc[i][j], 0, 0, 0);
        }
    }

    unsigned char* ab = attr + (size_t)b * COUT * NPIX;
    #pragma unroll
    for (int i = 0; i < 4; ++i) {
        int obase = o0 + wm * 64 + i * 16 + quad * 4;
        #pragma unroll
        for (int r = 0; r < 4; ++r) {
            int oo = obase + r;
            float sc = scale[oo], sh = shift[oo];
            #pragma unroll
            for (int j = 0; j < 4; ++j) {
                int n = n0 + wn * 64 + j * 16 + l16;
                float v = fmaxf(acc[i][j][r] * sc + sh, 0.0f);
                ab[(size_t)oo * NPIX + n] = f32_to_fp8(v);
            }
        }
    }
}

// ---------------- build pooling matrix P[b][m][pix] fp8 (x64) --------------
__global__ __launch_bounds__(256) void build_P(const float* __restrict__ boxes,
                                               unsigned char* __restrict__ P) {
    int br  = blockIdx.x;                // 0..159
    int m25 = blockIdx.y;                // 0..24
    int b   = br / NBOX;
    int m   = (br % NBOX) * 25 + m25;
    int p   = m25 / 5, q = m25 % 5;
    int t   = threadIdx.x;
    int y   = t >> 2;
    int x0  = (t & 3) * 16;
    const float* bx = boxes + (size_t)br * 4;
    int x1 = min(max((int)floorf(bx[0] * 0.125f), 0), 63);
    int y1 = min(max((int)floorf(bx[1] * 0.125f), 0), 63);
    int x2 = min(max((int)ceilf (bx[2] * 0.125f), 0), 63);
    int y2 = min(max((int)ceilf (bx[3] * 0.125f), 0), 63);
    if (x2 <= x1) x2 = min(x1 + 1, 64);
    if (y2 <= y1) y2 = min(y1 + 1, 64);
    int Lx = x2 - x1, Ly = y2 - y1;
    int sx = x1 + (q * Lx) / 5;
    int ex = x1 + ((q + 1) * Lx + 4) / 5;
    int sy = y1 + (p * Ly) / 5;
    int ey = y1 + ((p + 1) * Ly + 4) / 5;
    float wyv  = (y >= sy && y < ey) ? 1.0f / (float)(ey - sy) : 0.0f;
    float pval = 64.0f * wyv / (float)(ex - sx);
    float v[16];
    #pragma unroll
    for (int i = 0; i < 16; ++i) {
        int xi = x0 + i;
        v[i] = (xi >= sx && xi < ex) ? pval : 0.0f;
    }
    uint4 w;
    w.x = pack4_fp8(v[0],  v[1],  v[2],  v[3]);
    w.y = pack4_fp8(v[4],  v[5],  v[6],  v[7]);
    w.z = pack4_fp8(v[8],  v[9],  v[10], v[11]);
    w.w = pack4_fp8(v[12], v[13], v[14], v[15]);
    *(uint4*)(P + ((size_t)b * MPAD + m) * NPIX + y * FW + x0) = w;
}

// ---------------- fp8 pool GEMM, K-split x4, dense partials ----------------
__global__ __launch_bounds__(256) void pool_gemm(
        const unsigned char* __restrict__ P,
        const unsigned char* __restrict__ attr,
        float* __restrict__ part2) {
    __shared__ __align__(16) unsigned char lds_a[128 * 64];
    __shared__ __align__(16) unsigned char lds_b[128 * 64];
    int t  = threadIdx.x;
    int m0 = blockIdx.x * 128;
    int c0 = (blockIdx.y & 3) * 128;
    int seg = blockIdx.y >> 2;
    int b  = blockIdx.z;
    int wave = t >> 6, lane = t & 63;
    int wm = wave & 1, wn = wave >> 1;
    int quad = lane >> 4, l16 = lane & 15;
    const unsigned char* Pb = P + (size_t)b * MPAD * NPIX + seg * 1024;
    const unsigned char* ab = attr + (size_t)b * COUT * NPIX + seg * 1024;

    v4f acc[4][4];
    #pragma unroll
    for (int i = 0; i < 4; ++i)
        #pragma unroll
        for (int j = 0; j < 4; ++j) acc[i][j] = (v4f)0.0f;

    int row = t >> 2;
    int cg  = (t & 3) ^ ((row >> 1) & 3);
    const unsigned char* ga0 = Pb + (size_t)(m0 + row) * NPIX + cg * 16;
    const unsigned char* ga1 = Pb + (size_t)(m0 + row + 64) * NPIX + cg * 16;
    const unsigned char* gb0 = ab + (size_t)(c0 + row) * NPIX + cg * 16;
    const unsigned char* gb1 = ab + (size_t)(c0 + row + 64) * NPIX + cg * 16;
    unsigned char* la0 = lds_a + t * 16;
    unsigned char* la1 = lds_a + 4096 + t * 16;
    unsigned char* lb0 = lds_b + t * 16;
    unsigned char* lb1 = lds_b + 4096 + t * 16;

    int ra[4], rb[4];
    #pragma unroll
    for (int i = 0; i < 4; ++i) { ra[i] = wm * 64 + i * 16 + l16; rb[i] = wn * 64 + i * 16 + l16; }
    int q2 = quad >> 1, q1 = (quad & 1) * 8;

    for (int kt = 0; kt < 1024 / 64; ++kt) {
        __syncthreads();
        GLOAD_LDS16(ga0, la0);
        GLOAD_LDS16(ga1, la1);
        GLOAD_LDS16(gb0, lb0);
        GLOAD_LDS16(gb1, lb1);
        ga0 += 64; ga1 += 64; gb0 += 64; gb1 += 64;
        __syncthreads();

        #pragma unroll
        for (int s = 0; s < 2; ++s) {
            long af[4], bf[4];
            #pragma unroll
            for (int i = 0; i < 4; ++i) {
                int pa = (2 * s + q2) ^ ((ra[i] >> 1) & 3);
                af[i] = *(const long*)(lds_a + ra[i] * 64 + pa * 16 + q1);
                int pb = (2 * s + q2) ^ ((rb[i] >> 1) & 3);
                bf[i] = *(const long*)(lds_b + rb[i] * 64 + pb * 16 + q1);
            }
            #pragma unroll
            for (int i = 0; i < 4; ++i)
                #pragma unroll
                for (int j = 0; j < 4; ++j)
                    acc[i][j] = __builtin_amdgcn_mfma_f32_16x16x32_fp8_fp8(af[i], bf[j], acc[i][j], 0, 0, 0);
        }
    }

    float* pp = part2 + (((size_t)seg * BATCH + b) * MPAD) * COUT;
    #pragma unroll
    for (int i = 0; i < 4; ++i) {
        #pragma unroll
        for (int r = 0; r < 4; ++r) {
            int mrow = m0 + wm * 64 + i * 16 + quad * 4 + r;
            #pragma unroll
            for (int j = 0; j < 4; ++j) {
                int c = c0 + wn * 64 + j * 16 + l16;
                pp[(size_t)mrow * COUT + c] = acc[i][j][r];
            }
        }
    }
}

// ---------------- reduce 4 segs (/64 for P scaling), transpose to out ------
__global__ __launch_bounds__(256) void pool_reduce(const float* __restrict__ part2,
                                                   float* __restrict__ out) {
    const size_t SEG = (size_t)BATCH * MPAD * COUT;
    int i = blockIdx.x * 256 + threadIdx.x;
    int c = i & (COUT - 1);
    int m = (i >> 9) & (MPAD - 1);
    int b = i >> 17;
    if (m >= 250) return;
    float s = part2[i] + part2[i + SEG] + part2[i + 2 * SEG] + part2[i + 3 * SEG];
    int box = m / 25, bin = m - box * 25;
    out[640 + ((size_t)(b * NBOX + box) * COUT + c) * 25 + bin] = s * 0.015625f;
}

extern "C" void kernel_launch(void* const* d_in, const int* in_sizes, int n_in,
                              void* d_out, int out_size, void* d_ws, size_t ws_size,
                              hipStream_t stream) {
    const float* c3     = (const float*)d_in[0];
    const float* c4     = (const float*)d_in[1];
    const float* boxes  = (const float*)d_in[2];
    const float* w_conv = (const float*)d_in[3];
    const float* b_conv = (const float*)d_in[4];
    const float* bng    = (const float*)d_in[5];
    const float* bnb    = (const float*)d_in[6];
    const float* bnm    = (const float*)d_in[7];
    const float* bnv    = (const float*)d_in[8];
    float* out = (float*)d_out;

    char* ws = (char*)d_ws;
    // fp8 layout (no aliasing needed):
    unsigned char* fusedT = (unsigned char*)ws;                 // 100663296 B
    unsigned char* P      = (unsigned char*)(ws + 100663296);   //  16777216 B
    float*         part2  = (float*)(ws + 117440512);           //  33554432 B
    unsigned char* w8     = (unsigned char*)(ws + 150994944);   //    786432 B
    float*         scale  = (float*)(ws + 151781376);           //      2048 B
    float*         shift  = (float*)(ws + 151783424);           //      2048 B
    unsigned char* attr   = (unsigned char*)(ws + 151785472);   //  33554432 B

    hipMemcpyAsync(d_out, d_in[2], 640 * sizeof(float), hipMemcpyDeviceToDevice, stream);
    prep_bn<<<1, 512, 0, stream>>>(bng, bnb, bnm, bnv, b_conv, scale, shift);
    conv_w<<<(COUT * CIN / 4 + 255) / 256, 256, 0, stream>>>(w_conv, (uint32_t*)w8, COUT * CIN / 4);
    build_P<<<dim3(160, 25), 256, 0, stream>>>(boxes, P);
    build_fusedT<<<dim3(12, 64, 16), 256, 0, stream>>>(c3, c4, fusedT);
    gemm_bn_relu<<<dim3(32, 4, 16), 256, 0, stream>>>(w8, fusedT, scale, shift, attr);
    pool_gemm<<<dim3(2, 16, 16), 256, 0, stream>>>(P, attr, part2);
    pool_reduce<<<(BATCH * MPAD * COUT) / 256, 256, 0, stream>>>(part2, out);
    (void)in_sizes; (void)n_in; (void)out_size; (void)ws_size;
}

// Round 2
// 427.517 us; speedup vs baseline: 1.0685x; 1.0147x over previous
//
#include <hip/hip_runtime.h>
#include <stdint.h>

#define FH 64
#define FW 64
#define CIN 1536
#define C3C 512
#define C4C 1024
#define COUT 512
#define BATCH 16
#define NPIX 4096
#define NBOX 10
#define MPAD 256   // 10 boxes * 25 bins = 250, padded
#define NT 24      // CIN/64 K-tiles

typedef float v4f __attribute__((ext_vector_type(4)));

#define GLOAD_LDS16(g, l) __builtin_amdgcn_global_load_lds( \
    (const __attribute__((address_space(1))) void*)(g),     \
    (__attribute__((address_space(3))) void*)(l), 16, 0, 0)

#define BARRIER() asm volatile("s_barrier" ::: "memory")

// pack 4 floats -> 4 fp8 e4m3 bytes in one u32 (byte k = f[k])
__device__ __forceinline__ uint32_t pack4_fp8(float a, float b, float c, float d) {
    int lo = __builtin_amdgcn_cvt_pk_fp8_f32(a, b, 0, false);
    int v  = __builtin_amdgcn_cvt_pk_fp8_f32(c, d, lo, true);
    return (uint32_t)v;
}
__device__ __forceinline__ unsigned char f32_to_fp8(float a) {
    return (unsigned char)(__builtin_amdgcn_cvt_pk_fp8_f32(a, a, 0, false) & 0xff);
}

// ---------------- BN constant folding (W was scaled x16 -> scale/16) -------
__global__ void prep_bn(const float* __restrict__ bng, const float* __restrict__ bnb,
                        const float* __restrict__ bnm, const float* __restrict__ bnv,
                        const float* __restrict__ bconv,
                        float* __restrict__ scale, float* __restrict__ shift) {
    int o = threadIdx.x;
    if (o < COUT) {
        float inv = bng[o] / sqrtf(bnv[o] + 1e-5f);
        scale[o] = inv * 0.0625f;             // /16: W quantized as W*16
        shift[o] = bnb[o] + inv * (bconv[o] - bnm[o]);
    }
}

// ---------------- W f32 -> fp8 (x16) ---------------------------------------
__global__ void conv_w(const float* __restrict__ w, uint32_t* __restrict__ w8, int n4) {
    int i = blockIdx.x * 256 + threadIdx.x;
    if (i < n4) {
        float4 f = *(const float4*)(w + i * 4);
        w8[i] = pack4_fp8(f.x * 16.0f, f.y * 16.0f, f.z * 16.0f, f.w * 16.0f);
    }
}

// ---------------- build fusedT[b][pix][c] fp8 (K-major) --------------------
// tile: 128 channels x 64 px (one y row). LDS u32 = 4 packed channels.
__global__ __launch_bounds__(256) void build_fusedT(const float* __restrict__ c3,
                                                    const float* __restrict__ c4,
                                                    unsigned char* __restrict__ fusedT) {
    __shared__ uint32_t lds[64 * 36];
    int ct = blockIdx.x;          // 0..11; <4 -> c3, else c4
    int y  = blockIdx.y;
    int b  = blockIdx.z;
    int t  = threadIdx.x;
    int pg = t & 15;              // pixel quad: px 4pg..4pg+3
    int cq = t >> 4;              // 0..15; cquad = cq + 16r

    #pragma unroll
    for (int r = 0; r < 2; ++r) {
        int cquad = cq + 16 * r;
        float vv[4][4];           // [channel][pixel]
        if (ct < 4) {
            int ch = ct * 128 + 4 * cquad;
            const float* src = c3 + (((size_t)(b * C3C + ch) * FH + y) * FW) + 4 * pg;
            #pragma unroll
            for (int k = 0; k < 4; ++k) {
                float4 f = *(const float4*)(src + (size_t)k * (FH * FW));
                vv[k][0] = f.x; vv[k][1] = f.y; vv[k][2] = f.z; vv[k][3] = f.w;
            }
        } else {
            int ch = ct * 128 - 512 + 4 * cquad;
            int jy = y >> 1;
            int jyB = min(max(jy + ((y & 1) ? 1 : -1), 0), 31);
            int k0 = 2 * pg;
            int km = max(k0 - 1, 0), kp = min(k0 + 2, 31);
            const float* base = c4 + (size_t)(b * C4C + ch) * 1024;
            #pragma unroll
            for (int k = 0; k < 4; ++k) {
                const float* pc = base + (size_t)k * 1024;
                const float* r0 = pc + jy * 32;
                const float* r1 = pc + jyB * 32;
                float rbm = 0.75f * r0[km]     + 0.25f * r1[km];
                float rb0 = 0.75f * r0[k0]     + 0.25f * r1[k0];
                float rb1 = 0.75f * r0[k0 + 1] + 0.25f * r1[k0 + 1];
                float rbp = 0.75f * r0[kp]     + 0.25f * r1[kp];
                vv[k][0] = 0.75f * rb0 + 0.25f * rbm;
                vv[k][1] = 0.75f * rb0 + 0.25f * rb1;
                vv[k][2] = 0.75f * rb1 + 0.25f * rb0;
                vv[k][3] = 0.75f * rb1 + 0.25f * rbp;
            }
        }
        #pragma unroll
        for (int i = 0; i < 4; ++i)
            lds[(4 * pg + i) * 36 + cquad] = pack4_fp8(vv[0][i], vv[1][i], vv[2][i], vv[3][i]);
    }
    __syncthreads();
    // write: 64 px x 128 B; thread covers 2 x 16 B
    int g = t & 7;                 // 16-channel group
    #pragma unroll
    for (int rr = 0; rr < 2; ++rr) {
        int px = (t >> 3) + 32 * rr;
        uint4 w = *(const uint4*)(&lds[px * 36 + 4 * g]);
        *(uint4*)(fusedT + ((size_t)b * NPIX + y * FW + px) * CIN + ct * 128 + g * 16) = w;
    }
}

// ---------------- fp8 GEMM + BN + ReLU, 256x256 tile, 8-phase schedule -----
// T3+T4+T5 port: 4 phases per K-tile (one 64x32 C-quadrant each), one
// half-tile staged per phase 2 tiles ahead, single counted vmcnt(2) per
// tile (never 0 in steady state), raw s_barrier (no waitcnt drain),
// setprio(1) around MFMA clusters.
// LDS row remap so staging halves match read phases:
//   A: lds row = ih*128 + wm*64 + r   (half h=ih read only in phases with ih)
//   B: lds row = jh*128 + wn*32 + r
// Swizzle: chunk stored at position (chunk ^ ((ldsrow>>1)&3)); read key
// reduces to (l16>>1)&3 (same verified math as the 128-tile kernel).
__global__ __launch_bounds__(512, 2) void gemm_bn_relu(
        const unsigned char* __restrict__ w8,
        const unsigned char* __restrict__ fusedT,
        const float* __restrict__ scale, const float* __restrict__ shift,
        unsigned char* __restrict__ attr) {
    __shared__ __align__(16) unsigned char lds_a[2][16384];
    __shared__ __align__(16) unsigned char lds_b[2][16384];
    const int t  = threadIdx.x;
    const int n0 = blockIdx.x * 256;   // pixel tile
    const int o0 = blockIdx.y * 256;   // out-channel tile
    const int b  = blockIdx.z;
    const int wave = t >> 6, lane = t & 63;
    const int wm = wave & 1, wn = wave >> 1;   // 2 x 4 wave grid
    const int quad = lane >> 4, l16 = lane & 15;
    const int q2 = quad >> 1, q1 = (quad & 1) * 8;
    const int keyq = (l16 >> 1) & 3;
    // per-lane chunk byte offsets for s=0 / s=1
    const int cs0 = ((q2 ^ keyq) * 16) + q1;
    const int cs1 = (((2 + q2) ^ keyq) * 16) + q1;
    const unsigned char* fb = fusedT + (size_t)b * NPIX * CIN;

    // ---- staging addressing (512 threads cover one 128row x 64B half) ----
    const int lrow = t >> 2;                      // lds row within half
    const int cg   = (t & 3) ^ ((t >> 3) & 3);    // inverse-swizzled src chunk
    // A: global row = (t>>8)*128 + h*64 + (lrow&63)
    const size_t gA0 = (size_t)(o0 + ((t >> 8) << 7) + (lrow & 63)) * CIN + cg * 16;
    // B: global row = ((t>>7)&3)*64 + h*32 + (lrow&31)
    const size_t gB0 = (size_t)(n0 + (((t >> 7) & 3) << 6) + (lrow & 31)) * CIN + cg * 16;

#define STAGE_A(tt, h, d) GLOAD_LDS16(w8 + gA0 + (size_t)(h) * (64 * CIN) + (size_t)(tt) * 64, \
                                      &lds_a[d][(h) * 8192 + t * 16])
#define STAGE_B(tt, h, d) GLOAD_LDS16(fb + gB0 + (size_t)(h) * (32 * CIN) + (size_t)(tt) * 64, \
                                      &lds_b[d][(h) * 8192 + t * 16])
#define RD_A(base, ih, i, csel) (*(const long*)((base) + (((ih) * 128 + wm * 64 + (i) * 16 + l16) << 6) + (csel)))
#define RD_B(base, jh, j, csel) (*(const long*)((base) + (((jh) * 128 + wn * 32 + (j) * 16 + l16) << 6) + (csel)))

    v4f acc[8][4];
    #pragma unroll
    for (int i = 0; i < 8; ++i)
        #pragma unroll
        for (int j = 0; j < 4; ++j) acc[i][j] = (v4f)0.0f;

    // ---- prologue: tile0 all 4 halves + tile1 half0 pair ----
    STAGE_A(0, 0, 0); STAGE_B(0, 0, 0);
    STAGE_A(0, 1, 0); STAGE_B(0, 1, 0);
    STAGE_A(1, 0, 1); STAGE_B(1, 0, 1);
    asm volatile("s_waitcnt vmcnt(2)" ::: "memory");
    BARRIER();

    long a0[4][2], a1[4][2], b0[2][2], b1[2][2];

    for (int kt = 0; kt < NT; ++kt) {
        const unsigned char* bA = lds_a[kt & 1];
        const unsigned char* bB = lds_b[kt & 1];
        const int cur = kt & 1, nxt = cur ^ 1;

        // ---- phase 1: quadrant (ih=0, jh=0) ----
        #pragma unroll
        for (int i = 0; i < 4; ++i) { a0[i][0] = RD_A(bA, 0, i, cs0); a0[i][1] = RD_A(bA, 0, i, cs1); }
        #pragma unroll
        for (int j = 0; j < 2; ++j) { b0[j][0] = RD_B(bB, 0, j, cs0); b0[j][1] = RD_B(bB, 0, j, cs1); }
        if (kt + 1 < NT) STAGE_A(kt + 1, 1, nxt);
        BARRIER();
        __builtin_amdgcn_s_setprio(1);
        #pragma unroll
        for (int s = 0; s < 2; ++s)
            #pragma unroll
            for (int i = 0; i < 4; ++i)
                #pragma unroll
                for (int j = 0; j < 2; ++j)
                    acc[i][j] = __builtin_amdgcn_mfma_f32_16x16x32_fp8_fp8(a0[i][s], b0[j][s], acc[i][j], 0, 0, 0);
        __builtin_amdgcn_s_setprio(0);
        BARRIER();

        // ---- phase 2: quadrant (ih=0, jh=1) ----
        #pragma unroll
        for (int j = 0; j < 2; ++j) { b1[j][0] = RD_B(bB, 1, j, cs0); b1[j][1] = RD_B(bB, 1, j, cs1); }
        if (kt + 1 < NT) STAGE_B(kt + 1, 1, nxt);
        BARRIER();
        __builtin_amdgcn_s_setprio(1);
        #pragma unroll
        for (int s = 0; s < 2; ++s)
            #pragma unroll
            for (int i = 0; i < 4; ++i)
                #pragma unroll
                for (int j = 0; j < 2; ++j)
                    acc[i][2 + j] = __builtin_amdgcn_mfma_f32_16x16x32_fp8_fp8(a0[i][s], b1[j][s], acc[i][2 + j], 0, 0, 0);
        __builtin_amdgcn_s_setprio(0);
        BARRIER();

        // ---- phase 3: quadrant (ih=1, jh=0) ----
        #pragma unroll
        for (int i = 0; i < 4; ++i) { a1[i][0] = RD_A(bA, 1, i, cs0); a1[i][1] = RD_A(bA, 1, i, cs1); }
        if (kt + 2 < NT) STAGE_A(kt + 2, 0, cur);
        BARRIER();
        __builtin_amdgcn_s_setprio(1);
        #pragma unroll
        for (int s = 0; s < 2; ++s)
            #pragma unroll
            for (int i = 0; i < 4; ++i)
                #pragma unroll
                for (int j = 0; j < 2; ++j)
                    acc[4 + i][j] = __builtin_amdgcn_mfma_f32_16x16x32_fp8_fp8(a1[i][s], b0[j][s], acc[4 + i][j], 0, 0, 0);
        __builtin_amdgcn_s_setprio(0);
        BARRIER();

        // ---- phase 4: quadrant (ih=1, jh=1) ----
        if (kt + 2 < NT) STAGE_B(kt + 2, 0, cur);
        BARRIER();
        __builtin_amdgcn_s_setprio(1);
        #pragma unroll
        for (int s = 0; s < 2; ++s)
            #pragma unroll
            for (int i = 0; i < 4; ++i)
                #pragma unroll
                for (int j = 0; j < 2; ++j)
                    acc[4 + i][2 + j] = __builtin_amdgcn_mfma_f32_16x16x32_fp8_fp8(a1[i][s], b1[j][s], acc[4 + i][2 + j], 0, 0, 0);
        __builtin_amdgcn_s_setprio(0);
        // counted wait: next tile's 4 halves landed; 2 halves stay in flight
        if (kt < NT - 2) { asm volatile("s_waitcnt vmcnt(2)" ::: "memory"); }
        else            { asm volatile("s_waitcnt vmcnt(0)" ::: "memory"); }
        BARRIER();
    }

    // ---- epilogue: BN + ReLU + fp8 channel-major store ----
    unsigned char* ab = attr + (size_t)b * COUT * NPIX;
    #pragma unroll
    for (int a = 0; a < 8; ++a) {
        int obase = o0 + wm * 128 + (a >> 2) * 64 + (a & 3) * 16 + quad * 4;
        #pragma unroll
        for (int r = 0; r < 4; ++r) {
            int oo = obase + r;
            float sc = scale[oo], sh = shift[oo];
            #pragma unroll
            for (int bb = 0; bb < 4; ++bb) {
                int n = n0 + wn * 64 + (bb >> 1) * 32 + (bb & 1) * 16 + l16;
                float v = fmaxf(acc[a][bb][r] * sc + sh, 0.0f);
                ab[(size_t)oo * NPIX + n] = f32_to_fp8(v);
            }
        }
    }
#undef STAGE_A
#undef STAGE_B
#undef RD_A
#undef RD_B
}

// ---------------- build pooling matrix P[b][m][pix] fp8 (x64) --------------
__global__ __launch_bounds__(256) void build_P(const float* __restrict__ boxes,
                                               unsigned char* __restrict__ P) {
    int br  = blockIdx.x;                // 0..159
    int m25 = blockIdx.y;                // 0..24
    int b   = br / NBOX;
    int m   = (br % NBOX) * 25 + m25;
    int p   = m25 / 5, q = m25 % 5;
    int t   = threadIdx.x;
    int y   = t >> 2;
    int x0  = (t & 3) * 16;
    const float* bx = boxes + (size_t)br * 4;
    int x1 = min(max((int)floorf(bx[0] * 0.125f), 0), 63);
    int y1 = min(max((int)floorf(bx[1] * 0.125f), 0), 63);
    int x2 = min(max((int)ceilf (bx[2] * 0.125f), 0), 63);
    int y2 = min(max((int)ceilf (bx[3] * 0.125f), 0), 63);
    if (x2 <= x1) x2 = min(x1 + 1, 64);
    if (y2 <= y1) y2 = min(y1 + 1, 64);
    int Lx = x2 - x1, Ly = y2 - y1;
    int sx = x1 + (q * Lx) / 5;
    int ex = x1 + ((q + 1) * Lx + 4) / 5;
    int sy = y1 + (p * Ly) / 5;
    int ey = y1 + ((p + 1) * Ly + 4) / 5;
    float wyv  = (y >= sy && y < ey) ? 1.0f / (float)(ey - sy) : 0.0f;
    float pval = 64.0f * wyv / (float)(ex - sx);
    float v[16];
    #pragma unroll
    for (int i = 0; i < 16; ++i) {
        int xi = x0 + i;
        v[i] = (xi >= sx && xi < ex) ? pval : 0.0f;
    }
    uint4 w;
    w.x = pack4_fp8(v[0],  v[1],  v[2],  v[3]);
    w.y = pack4_fp8(v[4],  v[5],  v[6],  v[7]);
    w.z = pack4_fp8(v[8],  v[9],  v[10], v[11]);
    w.w = pack4_fp8(v[12], v[13], v[14], v[15]);
    *(uint4*)(P + ((size_t)b * MPAD + m) * NPIX + y * FW + x0) = w;
}

// ---------------- fp8 pool GEMM, K-split x4, dense partials ----------------
__global__ __launch_bounds__(256) void pool_gemm(
        const unsigned char* __restrict__ P,
        const unsigned char* __restrict__ attr,
        float* __restrict__ part2) {
    __shared__ __align__(16) unsigned char lds_a[128 * 64];
    __shared__ __align__(16) unsigned char lds_b[128 * 64];
    int t  = threadIdx.x;
    int m0 = blockIdx.x * 128;
    int c0 = (blockIdx.y & 3) * 128;
    int seg = blockIdx.y >> 2;
    int b  = blockIdx.z;
    int wave = t >> 6, lane = t & 63;
    int wm = wave & 1, wn = wave >> 1;
    int quad = lane >> 4, l16 = lane & 15;
    const unsigned char* Pb = P + (size_t)b * MPAD * NPIX + seg * 1024;
    const unsigned char* ab = attr + (size_t)b * COUT * NPIX + seg * 1024;

    v4f acc[4][4];
    #pragma unroll
    for (int i = 0; i < 4; ++i)
        #pragma unroll
        for (int j = 0; j < 4; ++j) acc[i][j] = (v4f)0.0f;

    int row = t >> 2;
    int cg  = (t & 3) ^ ((row >> 1) & 3);
    const unsigned char* ga0 = Pb + (size_t)(m0 + row) * NPIX + cg * 16;
    const unsigned char* ga1 = Pb + (size_t)(m0 + row + 64) * NPIX + cg * 16;
    const unsigned char* gb0 = ab + (size_t)(c0 + row) * NPIX + cg * 16;
    const unsigned char* gb1 = ab + (size_t)(c0 + row + 64) * NPIX + cg * 16;
    unsigned char* la0 = lds_a + t * 16;
    unsigned char* la1 = lds_a + 4096 + t * 16;
    unsigned char* lb0 = lds_b + t * 16;
    unsigned char* lb1 = lds_b + 4096 + t * 16;

    int ra[4], rb[4];
    #pragma unroll
    for (int i = 0; i < 4; ++i) { ra[i] = wm * 64 + i * 16 + l16; rb[i] = wn * 64 + i * 16 + l16; }
    int q2 = quad >> 1, q1 = (quad & 1) * 8;

    for (int kt = 0; kt < 1024 / 64; ++kt) {
        __syncthreads();
        GLOAD_LDS16(ga0, la0);
        GLOAD_LDS16(ga1, la1);
        GLOAD_LDS16(gb0, lb0);
        GLOAD_LDS16(gb1, lb1);
        ga0 += 64; ga1 += 64; gb0 += 64; gb1 += 64;
        __syncthreads();

        #pragma unroll
        for (int s = 0; s < 2; ++s) {
            long af[4], bf[4];
            #pragma unroll
            for (int i = 0; i < 4; ++i) {
                int pa = (2 * s + q2) ^ ((ra[i] >> 1) & 3);
                af[i] = *(const long*)(lds_a + ra[i] * 64 + pa * 16 + q1);
                int pb = (2 * s + q2) ^ ((rb[i] >> 1) & 3);
                bf[i] = *(const long*)(lds_b + rb[i] * 64 + pb * 16 + q1);
            }
            #pragma unroll
            for (int i = 0; i < 4; ++i)
                #pragma unroll
                for (int j = 0; j < 4; ++j)
                    acc[i][j] = __builtin_amdgcn_mfma_f32_16x16x32_fp8_fp8(af[i], bf[j], acc[i][j], 0, 0, 0);
        }
    }

    float* pp = part2 + (((size_t)seg * BATCH + b) * MPAD) * COUT;
    #pragma unroll
    for (int i = 0; i < 4; ++i) {
        #pragma unroll
        for (int r = 0; r < 4; ++r) {
            int mrow = m0 + wm * 64 + i * 16 + quad * 4 + r;
            #pragma unroll
            for (int j = 0; j < 4; ++j) {
                int c = c0 + wn * 64 + j * 16 + l16;
                pp[(size_t)mrow * COUT + c] = acc[i][j][r];
            }
        }
    }
}

// ---------------- reduce 4 segs (/64 for P scaling), transpose to out ------
__global__ __launch_bounds__(256) void pool_reduce(const float* __restrict__ part2,
                                                   float* __restrict__ out) {
    const size_t SEG = (size_t)BATCH * MPAD * COUT;
    int i = blockIdx.x * 256 + threadIdx.x;
    int c = i & (COUT - 1);
    int m = (i >> 9) & (MPAD - 1);
    int b = i >> 17;
    if (m >= 250) return;
    float s = part2[i] + part2[i + SEG] + part2[i + 2 * SEG] + part2[i + 3 * SEG];
    int box = m / 25, bin = m - box * 25;
    out[640 + ((size_t)(b * NBOX + box) * COUT + c) * 25 + bin] = s * 0.015625f;
}

extern "C" void kernel_launch(void* const* d_in, const int* in_sizes, int n_in,
                              void* d_out, int out_size, void* d_ws, size_t ws_size,
                              hipStream_t stream) {
    const float* c3     = (const float*)d_in[0];
    const float* c4     = (const float*)d_in[1];
    const float* boxes  = (const float*)d_in[2];
    const float* w_conv = (const float*)d_in[3];
    const float* b_conv = (const float*)d_in[4];
    const float* bng    = (const float*)d_in[5];
    const float* bnb    = (const float*)d_in[6];
    const float* bnm    = (const float*)d_in[7];
    const float* bnv    = (const float*)d_in[8];
    float* out = (float*)d_out;

    char* ws = (char*)d_ws;
    // fp8 layout (no aliasing needed):
    unsigned char* fusedT = (unsigned char*)ws;                 // 100663296 B
    unsigned char* P      = (unsigned char*)(ws + 100663296);   //  16777216 B
    float*         part2  = (float*)(ws + 117440512);           //  33554432 B
    unsigned char* w8     = (unsigned char*)(ws + 150994944);   //    786432 B
    float*         scale  = (float*)(ws + 151781376);           //      2048 B
    float*         shift  = (float*)(ws + 151783424);           //      2048 B
    unsigned char* attr   = (unsigned char*)(ws + 151785472);   //  33554432 B

    hipMemcpyAsync(d_out, d_in[2], 640 * sizeof(float), hipMemcpyDeviceToDevice, stream);
    prep_bn<<<1, 512, 0, stream>>>(bng, bnb, bnm, bnv, b_conv, scale, shift);
    conv_w<<<(COUT * CIN / 4 + 255) / 256, 256, 0, stream>>>(w_conv, (uint32_t*)w8, COUT * CIN / 4);
    build_P<<<dim3(160, 25), 256, 0, stream>>>(boxes, P);
    build_fusedT<<<dim3(12, 64, 16), 256, 0, stream>>>(c3, c4, fusedT);
    gemm_bn_relu<<<dim3(16, 2, 16), 512, 0, stream>>>(w8, fusedT, scale, shift, attr);
    pool_gemm<<<dim3(2, 16, 16), 256, 0, stream>>>(P, attr, part2);
    pool_reduce<<<(BATCH * MPAD * COUT) / 256, 256, 0, stream>>>(part2, out);
    (void)in_sizes; (void)n_in; (void)out_size; (void)ws_size;
}

// Round 3
// 412.645 us; speedup vs baseline: 1.1071x; 1.0360x over previous
//
#include <hip/hip_runtime.h>
#include <stdint.h>

#define FH 64
#define FW 64
#define CIN 1536
#define C3C 512
#define C4C 1024
#define COUT 512
#define BATCH 16
#define NPIX 4096
#define NBOX 10
#define MPAD 256   // 10 boxes * 25 bins = 250, padded
#define NT 24      // CIN/64 K-tiles

typedef float v4f __attribute__((ext_vector_type(4)));

#define GLOAD_LDS16(g, l) __builtin_amdgcn_global_load_lds( \
    (const __attribute__((address_space(1))) void*)(g),     \
    (__attribute__((address_space(3))) void*)(l), 16, 0, 0)

#define BARRIER() asm volatile("s_barrier" ::: "memory")

// pack 4 floats -> 4 fp8 e4m3 bytes in one u32 (byte k = f[k])
__device__ __forceinline__ uint32_t pack4_fp8(float a, float b, float c, float d) {
    int lo = __builtin_amdgcn_cvt_pk_fp8_f32(a, b, 0, false);
    int v  = __builtin_amdgcn_cvt_pk_fp8_f32(c, d, lo, true);
    return (uint32_t)v;
}
__device__ __forceinline__ unsigned char f32_to_fp8(float a) {
    return (unsigned char)(__builtin_amdgcn_cvt_pk_fp8_f32(a, a, 0, false) & 0xff);
}

// ---------------- BN constant folding (W was scaled x16 -> scale/16) -------
__global__ void prep_bn(const float* __restrict__ bng, const float* __restrict__ bnb,
                        const float* __restrict__ bnm, const float* __restrict__ bnv,
                        const float* __restrict__ bconv,
                        float* __restrict__ scale, float* __restrict__ shift) {
    int o = threadIdx.x;
    if (o < COUT) {
        float inv = bng[o] / sqrtf(bnv[o] + 1e-5f);
        scale[o] = inv * 0.0625f;             // /16: W quantized as W*16
        shift[o] = bnb[o] + inv * (bconv[o] - bnm[o]);
    }
}

// ---------------- W f32 -> fp8 (x16) ---------------------------------------
__global__ void conv_w(const float* __restrict__ w, uint32_t* __restrict__ w8, int n4) {
    int i = blockIdx.x * 256 + threadIdx.x;
    if (i < n4) {
        float4 f = *(const float4*)(w + i * 4);
        w8[i] = pack4_fp8(f.x * 16.0f, f.y * 16.0f, f.z * 16.0f, f.w * 16.0f);
    }
}

// ---------------- build fusedT[b][pix][c] fp8 (K-major) --------------------
// tile: 128 channels x 64 px (one y row). LDS u32 = 4 packed channels.
// c4 path: float2 loads + cross-lane shuffles replace 8 scalar gathers/ch
// (was VMEM-issue-bound: 64 scalar loads/thread, 2.2 TB/s @ 15% VALU).
// LDS chunk index XOR-swizzled by (px>>1)&7: write was 8-way conflicted
// (row stride 36 words -> 144*pg mod 32 = 16*(pg&1), pg bits 1-3 lost);
// key injects pg bits 1-3 into chunk bits -> 2-way (free). Read stays
// 16B-aligned, 8 words/bank (optimal).
__global__ __launch_bounds__(256) void build_fusedT(const float* __restrict__ c3,
                                                    const float* __restrict__ c4,
                                                    unsigned char* __restrict__ fusedT) {
    __shared__ uint32_t lds[64 * 36];
    int ct = blockIdx.x;          // 0..11; <4 -> c3, else c4
    int y  = blockIdx.y;
    int b  = blockIdx.z;
    int t  = threadIdx.x;
    int pg = t & 15;              // pixel quad: px 4pg..4pg+3
    int cq = t >> 4;              // 0..15; cquad = cq + 16r

    #pragma unroll
    for (int r = 0; r < 2; ++r) {
        int cquad = cq + 16 * r;
        float vv[4][4];           // [channel][pixel]
        if (ct < 4) {
            int ch = ct * 128 + 4 * cquad;
            const float* src = c3 + (((size_t)(b * C3C + ch) * FH + y) * FW) + 4 * pg;
            #pragma unroll
            for (int k = 0; k < 4; ++k) {
                float4 f = *(const float4*)(src + (size_t)k * (FH * FW));
                vv[k][0] = f.x; vv[k][1] = f.y; vv[k][2] = f.z; vv[k][3] = f.w;
            }
        } else {
            int ch = ct * 128 - 512 + 4 * cquad;
            int jy = y >> 1;
            int jyB = min(max(jy + ((y & 1) ? 1 : -1), 0), 31);
            const float* base = c4 + (size_t)(b * C4C + ch) * 1024;
            #pragma unroll
            for (int k = 0; k < 4; ++k) {
                const float* pc = base + (size_t)k * 1024;
                float2 f0 = *(const float2*)(pc + jy * 32 + 2 * pg);
                float2 f1 = *(const float2*)(pc + jyB * 32 + 2 * pg);
                float rbA = 0.75f * f0.x + 0.25f * f1.x;   // rb[2pg]
                float rbB = 0.75f * f0.y + 0.25f * f1.y;   // rb[2pg+1]
                float rbm = __shfl_up(rbB, 1, 16);          // rb[2pg-1]
                float rbp = __shfl_down(rbA, 1, 16);        // rb[2pg+2]
                if (pg == 0)  rbm = rbA;                    // km clamp
                if (pg == 15) rbp = rbB;                    // kp clamp
                vv[k][0] = 0.75f * rbA + 0.25f * rbm;
                vv[k][1] = 0.75f * rbA + 0.25f * rbB;
                vv[k][2] = 0.75f * rbB + 0.25f * rbA;
                vv[k][3] = 0.75f * rbB + 0.25f * rbp;
            }
        }
        #pragma unroll
        for (int i = 0; i < 4; ++i) {
            int px = 4 * pg + i;
            lds[px * 36 + 4 * ((cquad >> 2) ^ ((px >> 1) & 7)) + (cquad & 3)] =
                pack4_fp8(vv[0][i], vv[1][i], vv[2][i], vv[3][i]);
        }
    }
    __syncthreads();
    // write: 64 px x 128 B; thread covers 2 x 16 B
    int g = t & 7;                 // 16-channel group
    #pragma unroll
    for (int rr = 0; rr < 2; ++rr) {
        int px = (t >> 3) + 32 * rr;
        uint4 w = *(const uint4*)(&lds[px * 36 + 4 * (g ^ ((px >> 1) & 7))]);
        *(uint4*)(fusedT + ((size_t)b * NPIX + y * FW + px) * CIN + ct * 128 + g * 16) = w;
    }
}

// ---------------- fp8 GEMM + BN + ReLU, 256x256 tile, 8-phase schedule -----
// T3+T4+T5 port: 4 phases per K-tile (one 64x32 C-quadrant each), one
// half-tile staged per phase 2 tiles ahead, single counted vmcnt(2) per
// tile (never 0 in steady state), raw s_barrier (no waitcnt drain),
// setprio(1) around MFMA clusters.
__global__ __launch_bounds__(512, 2) void gemm_bn_relu(
        const unsigned char* __restrict__ w8,
        const unsigned char* __restrict__ fusedT,
        const float* __restrict__ scale, const float* __restrict__ shift,
        unsigned char* __restrict__ attr) {
    __shared__ __align__(16) unsigned char lds_a[2][16384];
    __shared__ __align__(16) unsigned char lds_b[2][16384];
    const int t  = threadIdx.x;
    const int n0 = blockIdx.x * 256;   // pixel tile
    const int o0 = blockIdx.y * 256;   // out-channel tile
    const int b  = blockIdx.z;
    const int wave = t >> 6, lane = t & 63;
    const int wm = wave & 1, wn = wave >> 1;   // 2 x 4 wave grid
    const int quad = lane >> 4, l16 = lane & 15;
    const int q2 = quad >> 1, q1 = (quad & 1) * 8;
    const int keyq = (l16 >> 1) & 3;
    // per-lane chunk byte offsets for s=0 / s=1
    const int cs0 = ((q2 ^ keyq) * 16) + q1;
    const int cs1 = (((2 + q2) ^ keyq) * 16) + q1;
    const unsigned char* fb = fusedT + (size_t)b * NPIX * CIN;

    // ---- staging addressing (512 threads cover one 128row x 64B half) ----
    const int lrow = t >> 2;                      // lds row within half
    const int cg   = (t & 3) ^ ((t >> 3) & 3);    // inverse-swizzled src chunk
    // A: global row = (t>>8)*128 + h*64 + (lrow&63)
    const size_t gA0 = (size_t)(o0 + ((t >> 8) << 7) + (lrow & 63)) * CIN + cg * 16;
    // B: global row = ((t>>7)&3)*64 + h*32 + (lrow&31)
    const size_t gB0 = (size_t)(n0 + (((t >> 7) & 3) << 6) + (lrow & 31)) * CIN + cg * 16;

#define STAGE_A(tt, h, d) GLOAD_LDS16(w8 + gA0 + (size_t)(h) * (64 * CIN) + (size_t)(tt) * 64, \
                                      &lds_a[d][(h) * 8192 + t * 16])
#define STAGE_B(tt, h, d) GLOAD_LDS16(fb + gB0 + (size_t)(h) * (32 * CIN) + (size_t)(tt) * 64, \
                                      &lds_b[d][(h) * 8192 + t * 16])
#define RD_A(base, ih, i, csel) (*(const long*)((base) + (((ih) * 128 + wm * 64 + (i) * 16 + l16) << 6) + (csel)))
#define RD_B(base, jh, j, csel) (*(const long*)((base) + (((jh) * 128 + wn * 32 + (j) * 16 + l16) << 6) + (csel)))

    v4f acc[8][4];
    #pragma unroll
    for (int i = 0; i < 8; ++i)
        #pragma unroll
        for (int j = 0; j < 4; ++j) acc[i][j] = (v4f)0.0f;

    // ---- prologue: tile0 all 4 halves + tile1 half0 pair ----
    STAGE_A(0, 0, 0); STAGE_B(0, 0, 0);
    STAGE_A(0, 1, 0); STAGE_B(0, 1, 0);
    STAGE_A(1, 0, 1); STAGE_B(1, 0, 1);
    asm volatile("s_waitcnt vmcnt(2)" ::: "memory");
    BARRIER();

    long a0[4][2], a1[4][2], b0[2][2], b1[2][2];

    for (int kt = 0; kt < NT; ++kt) {
        const unsigned char* bA = lds_a[kt & 1];
        const unsigned char* bB = lds_b[kt & 1];
        const int cur = kt & 1, nxt = cur ^ 1;

        // ---- phase 1: quadrant (ih=0, jh=0) ----
        #pragma unroll
        for (int i = 0; i < 4; ++i) { a0[i][0] = RD_A(bA, 0, i, cs0); a0[i][1] = RD_A(bA, 0, i, cs1); }
        #pragma unroll
        for (int j = 0; j < 2; ++j) { b0[j][0] = RD_B(bB, 0, j, cs0); b0[j][1] = RD_B(bB, 0, j, cs1); }
        if (kt + 1 < NT) STAGE_A(kt + 1, 1, nxt);
        BARRIER();
        __builtin_amdgcn_s_setprio(1);
        #pragma unroll
        for (int s = 0; s < 2; ++s)
            #pragma unroll
            for (int i = 0; i < 4; ++i)
                #pragma unroll
                for (int j = 0; j < 2; ++j)
                    acc[i][j] = __builtin_amdgcn_mfma_f32_16x16x32_fp8_fp8(a0[i][s], b0[j][s], acc[i][j], 0, 0, 0);
        __builtin_amdgcn_s_setprio(0);
        BARRIER();

        // ---- phase 2: quadrant (ih=0, jh=1) ----
        #pragma unroll
        for (int j = 0; j < 2; ++j) { b1[j][0] = RD_B(bB, 1, j, cs0); b1[j][1] = RD_B(bB, 1, j, cs1); }
        if (kt + 1 < NT) STAGE_B(kt + 1, 1, nxt);
        BARRIER();
        __builtin_amdgcn_s_setprio(1);
        #pragma unroll
        for (int s = 0; s < 2; ++s)
            #pragma unroll
            for (int i = 0; i < 4; ++i)
                #pragma unroll
                for (int j = 0; j < 2; ++j)
                    acc[i][2 + j] = __builtin_amdgcn_mfma_f32_16x16x32_fp8_fp8(a0[i][s], b1[j][s], acc[i][2 + j], 0, 0, 0);
        __builtin_amdgcn_s_setprio(0);
        BARRIER();

        // ---- phase 3: quadrant (ih=1, jh=0) ----
        #pragma unroll
        for (int i = 0; i < 4; ++i) { a1[i][0] = RD_A(bA, 1, i, cs0); a1[i][1] = RD_A(bA, 1, i, cs1); }
        if (kt + 2 < NT) STAGE_A(kt + 2, 0, cur);
        BARRIER();
        __builtin_amdgcn_s_setprio(1);
        #pragma unroll
        for (int s = 0; s < 2; ++s)
            #pragma unroll
            for (int i = 0; i < 4; ++i)
                #pragma unroll
                for (int j = 0; j < 2; ++j)
                    acc[4 + i][j] = __builtin_amdgcn_mfma_f32_16x16x32_fp8_fp8(a1[i][s], b0[j][s], acc[4 + i][j], 0, 0, 0);
        __builtin_amdgcn_s_setprio(0);
        BARRIER();

        // ---- phase 4: quadrant (ih=1, jh=1) ----
        if (kt + 2 < NT) STAGE_B(kt + 2, 0, cur);
        BARRIER();
        __builtin_amdgcn_s_setprio(1);
        #pragma unroll
        for (int s = 0; s < 2; ++s)
            #pragma unroll
            for (int i = 0; i < 4; ++i)
                #pragma unroll
                for (int j = 0; j < 2; ++j)
                    acc[4 + i][2 + j] = __builtin_amdgcn_mfma_f32_16x16x32_fp8_fp8(a1[i][s], b1[j][s], acc[4 + i][2 + j], 0, 0, 0);
        __builtin_amdgcn_s_setprio(0);
        // counted wait: next tile's 4 halves landed; 2 halves stay in flight
        if (kt < NT - 2) { asm volatile("s_waitcnt vmcnt(2)" ::: "memory"); }
        else            { asm volatile("s_waitcnt vmcnt(0)" ::: "memory"); }
        BARRIER();
    }

    // ---- epilogue: BN + ReLU + fp8 channel-major store ----
    unsigned char* ab = attr + (size_t)b * COUT * NPIX;
    #pragma unroll
    for (int a = 0; a < 8; ++a) {
        int obase = o0 + wm * 128 + (a >> 2) * 64 + (a & 3) * 16 + quad * 4;
        #pragma unroll
        for (int r = 0; r < 4; ++r) {
            int oo = obase + r;
            float sc = scale[oo], sh = shift[oo];
            #pragma unroll
            for (int bb = 0; bb < 4; ++bb) {
                int n = n0 + wn * 64 + (bb >> 1) * 32 + (bb & 1) * 16 + l16;
                float v = fmaxf(acc[a][bb][r] * sc + sh, 0.0f);
                ab[(size_t)oo * NPIX + n] = f32_to_fp8(v);
            }
        }
    }
#undef STAGE_A
#undef STAGE_B
#undef RD_A
#undef RD_B
}

// ---------------- build pooling matrix P[b][m][pix] fp8 (x64) --------------
__global__ __launch_bounds__(256) void build_P(const float* __restrict__ boxes,
                                               unsigned char* __restrict__ P) {
    int br  = blockIdx.x;                // 0..159
    int m25 = blockIdx.y;                // 0..24
    int b   = br / NBOX;
    int m   = (br % NBOX) * 25 + m25;
    int p   = m25 / 5, q = m25 % 5;
    int t   = threadIdx.x;
    int y   = t >> 2;
    int x0  = (t & 3) * 16;
    const float* bx = boxes + (size_t)br * 4;
    int x1 = min(max((int)floorf(bx[0] * 0.125f), 0), 63);
    int y1 = min(max((int)floorf(bx[1] * 0.125f), 0), 63);
    int x2 = min(max((int)ceilf (bx[2] * 0.125f), 0), 63);
    int y2 = min(max((int)ceilf (bx[3] * 0.125f), 0), 63);
    if (x2 <= x1) x2 = min(x1 + 1, 64);
    if (y2 <= y1) y2 = min(y1 + 1, 64);
    int Lx = x2 - x1, Ly = y2 - y1;
    int sx = x1 + (q * Lx) / 5;
    int ex = x1 + ((q + 1) * Lx + 4) / 5;
    int sy = y1 + (p * Ly) / 5;
    int ey = y1 + ((p + 1) * Ly + 4) / 5;
    float wyv  = (y >= sy && y < ey) ? 1.0f / (float)(ey - sy) : 0.0f;
    float pval = 64.0f * wyv / (float)(ex - sx);
    float v[16];
    #pragma unroll
    for (int i = 0; i < 16; ++i) {
        int xi = x0 + i;
        v[i] = (xi >= sx && xi < ex) ? pval : 0.0f;
    }
    uint4 w;
    w.x = pack4_fp8(v[0],  v[1],  v[2],  v[3]);
    w.y = pack4_fp8(v[4],  v[5],  v[6],  v[7]);
    w.z = pack4_fp8(v[8],  v[9],  v[10], v[11]);
    w.w = pack4_fp8(v[12], v[13], v[14], v[15]);
    *(uint4*)(P + ((size_t)b * MPAD + m) * NPIX + y * FW + x0) = w;
}

// ---------------- fp8 pool GEMM, K-split x4, dense partials ----------------
__global__ __launch_bounds__(256) void pool_gemm(
        const unsigned char* __restrict__ P,
        const unsigned char* __restrict__ attr,
        float* __restrict__ part2) {
    __shared__ __align__(16) unsigned char lds_a[128 * 64];
    __shared__ __align__(16) unsigned char lds_b[128 * 64];
    int t  = threadIdx.x;
    int m0 = blockIdx.x * 128;
    int c0 = (blockIdx.y & 3) * 128;
    int seg = blockIdx.y >> 2;
    int b  = blockIdx.z;
    int wave = t >> 6, lane = t & 63;
    int wm = wave & 1, wn = wave >> 1;
    int quad = lane >> 4, l16 = lane & 15;
    const unsigned char* Pb = P + (size_t)b * MPAD * NPIX + seg * 1024;
    const unsigned char* ab = attr + (size_t)b * COUT * NPIX + seg * 1024;

    v4f acc[4][4];
    #pragma unroll
    for (int i = 0; i < 4; ++i)
        #pragma unroll
        for (int j = 0; j < 4; ++j) acc[i][j] = (v4f)0.0f;

    int row = t >> 2;
    int cg  = (t & 3) ^ ((row >> 1) & 3);
    const unsigned char* ga0 = Pb + (size_t)(m0 + row) * NPIX + cg * 16;
    const unsigned char* ga1 = Pb + (size_t)(m0 + row + 64) * NPIX + cg * 16;
    const unsigned char* gb0 = ab + (size_t)(c0 + row) * NPIX + cg * 16;
    const unsigned char* gb1 = ab + (size_t)(c0 + row + 64) * NPIX + cg * 16;
    unsigned char* la0 = lds_a + t * 16;
    unsigned char* la1 = lds_a + 4096 + t * 16;
    unsigned char* lb0 = lds_b + t * 16;
    unsigned char* lb1 = lds_b + 4096 + t * 16;

    int ra[4], rb[4];
    #pragma unroll
    for (int i = 0; i < 4; ++i) { ra[i] = wm * 64 + i * 16 + l16; rb[i] = wn * 64 + i * 16 + l16; }
    int q2 = quad >> 1, q1 = (quad & 1) * 8;

    for (int kt = 0; kt < 1024 / 64; ++kt) {
        __syncthreads();
        GLOAD_LDS16(ga0, la0);
        GLOAD_LDS16(ga1, la1);
        GLOAD_LDS16(gb0, lb0);
        GLOAD_LDS16(gb1, lb1);
        ga0 += 64; ga1 += 64; gb0 += 64; gb1 += 64;
        __syncthreads();

        #pragma unroll
        for (int s = 0; s < 2; ++s) {
            long af[4], bf[4];
            #pragma unroll
            for (int i = 0; i < 4; ++i) {
                int pa = (2 * s + q2) ^ ((ra[i] >> 1) & 3);
                af[i] = *(const long*)(lds_a + ra[i] * 64 + pa * 16 + q1);
                int pb = (2 * s + q2) ^ ((rb[i] >> 1) & 3);
                bf[i] = *(const long*)(lds_b + rb[i] * 64 + pb * 16 + q1);
            }
            #pragma unroll
            for (int i = 0; i < 4; ++i)
                #pragma unroll
                for (int j = 0; j < 4; ++j)
                    acc[i][j] = __builtin_amdgcn_mfma_f32_16x16x32_fp8_fp8(af[i], bf[j], acc[i][j], 0, 0, 0);
        }
    }

    float* pp = part2 + (((size_t)seg * BATCH + b) * MPAD) * COUT;
    #pragma unroll
    for (int i = 0; i < 4; ++i) {
        #pragma unroll
        for (int r = 0; r < 4; ++r) {
            int mrow = m0 + wm * 64 + i * 16 + quad * 4 + r;
            #pragma unroll
            for (int j = 0; j < 4; ++j) {
                int c = c0 + wn * 64 + j * 16 + l16;
                pp[(size_t)mrow * COUT + c] = acc[i][j][r];
            }
        }
    }
}

// ---------------- reduce 4 segs (/64 for P scaling), transpose to out ------
__global__ __launch_bounds__(256) void pool_reduce(const float* __restrict__ part2,
                                                   float* __restrict__ out) {
    const size_t SEG = (size_t)BATCH * MPAD * COUT;
    int i = blockIdx.x * 256 + threadIdx.x;
    int c = i & (COUT - 1);
    int m = (i >> 9) & (MPAD - 1);
    int b = i >> 17;
    if (m >= 250) return;
    float s = part2[i] + part2[i + SEG] + part2[i + 2 * SEG] + part2[i + 3 * SEG];
    int box = m / 25, bin = m - box * 25;
    out[640 + ((size_t)(b * NBOX + box) * COUT + c) * 25 + bin] = s * 0.015625f;
}

extern "C" void kernel_launch(void* const* d_in, const int* in_sizes, int n_in,
                              void* d_out, int out_size, void* d_ws, size_t ws_size,
                              hipStream_t stream) {
    const float* c3     = (const float*)d_in[0];
    const float* c4     = (const float*)d_in[1];
    const float* boxes  = (const float*)d_in[2];
    const float* w_conv = (const float*)d_in[3];
    const float* b_conv = (const float*)d_in[4];
    const float* bng    = (const float*)d_in[5];
    const float* bnb    = (const float*)d_in[6];
    const float* bnm    = (const float*)d_in[7];
    const float* bnv    = (const float*)d_in[8];
    float* out = (float*)d_out;

    char* ws = (char*)d_ws;
    // fp8 layout (no aliasing needed):
    unsigned char* fusedT = (unsigned char*)ws;                 // 100663296 B
    unsigned char* P      = (unsigned char*)(ws + 100663296);   //  16777216 B
    float*         part2  = (float*)(ws + 117440512);           //  33554432 B
    unsigned char* w8     = (unsigned char*)(ws + 150994944);   //    786432 B
    float*         scale  = (float*)(ws + 151781376);           //      2048 B
    float*         shift  = (float*)(ws + 151783424);           //      2048 B
    unsigned char* attr   = (unsigned char*)(ws + 151785472);   //  33554432 B

    hipMemcpyAsync(d_out, d_in[2], 640 * sizeof(float), hipMemcpyDeviceToDevice, stream);
    prep_bn<<<1, 512, 0, stream>>>(bng, bnb, bnm, bnv, b_conv, scale, shift);
    conv_w<<<(COUT * CIN / 4 + 255) / 256, 256, 0, stream>>>(w_conv, (uint32_t*)w8, COUT * CIN / 4);
    build_P<<<dim3(160, 25), 256, 0, stream>>>(boxes, P);
    build_fusedT<<<dim3(12, 64, 16), 256, 0, stream>>>(c3, c4, fusedT);
    gemm_bn_relu<<<dim3(16, 2, 16), 512, 0, stream>>>(w8, fusedT, scale, shift, attr);
    pool_gemm<<<dim3(2, 16, 16), 256, 0, stream>>>(P, attr, part2);
    pool_reduce<<<(BATCH * MPAD * COUT) / 256, 256, 0, stream>>>(part2, out);
    (void)in_sizes; (void)n_in; (void)out_size; (void)ws_size;
}